// Round 5
// baseline (163.990 us; speedup 1.0000x reference)
//
#include <hip/hip_runtime.h>
#include <hip/hip_bf16.h>
#include <math.h>

#define H_ 14
#define W_ 14
#define HW_ 196
#define CIN_ 1024
#define CMID_ 256
#define NCLS_ 27
#define NB_ 16
#define ROIS_ 980
#define M_ 3136
#define FEAT_ 2304
#define NROI_ (NB_ * ROIS_)   // 15680

typedef unsigned short u16;
typedef __attribute__((ext_vector_type(8))) short bf16x8;
typedef __attribute__((ext_vector_type(4))) float f32x4;

__device__ __forceinline__ float bf2f(u16 u) {
    union { unsigned int i; float f; } x; x.i = ((unsigned int)u) << 16; return x.f;
}
__device__ __forceinline__ u16 f2bf(float f) {
    __hip_bfloat16 h = __float2bfloat16(f);
    return *reinterpret_cast<u16*>(&h);
}
__device__ __forceinline__ int rfl_i(int v) { return __builtin_amdgcn_readfirstlane(v); }

// ---------------- prep: flat fp32 -> bf16 ----------------
__global__ __launch_bounds__(256) void k_f32_to_bf16(const float* __restrict__ in,
                                                     u16* __restrict__ out) {
    int i = blockIdx.x * 256 + threadIdx.x;
    out[i] = f2bf(in[i]);
}

// ---------------- prep: wfc [27][2304 CHW] -> bf16 [32][2304 bin-major], zero-pad ----------------
__global__ __launch_bounds__(256) void k_prep_wfc(const float* __restrict__ wfc,
                                                  u16* __restrict__ wfcb) {
    int idx = blockIdx.x * 256 + threadIdx.x;       // cls*2304 + k, k = bin*256 + c
    int cls = idx / FEAT_;
    int k = idx - cls * FEAT_;
    int c = k & 255, bin = k >> 8;
    float v = (cls < NCLS_) ? wfc[cls * FEAT_ + c * 9 + bin] : 0.0f;
    wfcb[idx] = f2bf(v);
}

// ---------------- K0: NCHW fp32 -> NHWC bf16 ----------------
__global__ __launch_bounds__(256) void k_nchw_to_nhwc(const float* __restrict__ in,
                                                      u16* __restrict__ out) {
    int idx = blockIdx.x * 256 + threadIdx.x;   // m*1024 + c
    int m = idx >> 10, c = idx & 1023;
    int b = m / HW_, hw = m - b * HW_;
    out[idx] = f2bf(in[(b * CIN_ + c) * HW_ + hw]);
}

// ---------------- K1/K2: GEMM (A[M,K] * Bw[N,K]^T) + BN epilogue ----------------
template<bool OUT_F32>
__global__ __launch_bounds__(256) void k_gemm_bn(
    const u16* __restrict__ A, const u16* __restrict__ Bw,
    const float* __restrict__ gg, const float* __restrict__ bb,
    const float* __restrict__ mm, const float* __restrict__ vv,
    void* __restrict__ outp, int N, int K)
{
    __shared__ u16 As[64][40];
    __shared__ u16 Bs[64][40];
    const int row0 = blockIdx.y * 64, col0 = blockIdx.x * 64;
    const int t = threadIdx.x;
    const int lr = t >> 2, lk = (t & 3) * 8;
    const int wave = t >> 6, lane = t & 63;
    const int wr = (wave >> 1) * 32, wc = (wave & 1) * 32;
    const int fr = lane & 15, fk = (lane >> 4) * 8;
    f32x4 acc[2][2] = {};
    const u16* Aptr = A + (size_t)(row0 + lr) * K + lk;
    const u16* Bptr = Bw + (size_t)(col0 + lr) * K + lk;
    for (int k0 = 0; k0 < K; k0 += 32) {
        *reinterpret_cast<uint4*>(&As[lr][lk]) = *reinterpret_cast<const uint4*>(Aptr + k0);
        *reinterpret_cast<uint4*>(&Bs[lr][lk]) = *reinterpret_cast<const uint4*>(Bptr + k0);
        __syncthreads();
        bf16x8 a0 = *reinterpret_cast<bf16x8*>(&As[wr + fr][fk]);
        bf16x8 a1 = *reinterpret_cast<bf16x8*>(&As[wr + 16 + fr][fk]);
        bf16x8 b0 = *reinterpret_cast<bf16x8*>(&Bs[wc + fr][fk]);
        bf16x8 b1 = *reinterpret_cast<bf16x8*>(&Bs[wc + 16 + fr][fk]);
        acc[0][0] = __builtin_amdgcn_mfma_f32_16x16x32_bf16(a0, b0, acc[0][0], 0, 0, 0);
        acc[0][1] = __builtin_amdgcn_mfma_f32_16x16x32_bf16(a0, b1, acc[0][1], 0, 0, 0);
        acc[1][0] = __builtin_amdgcn_mfma_f32_16x16x32_bf16(a1, b0, acc[1][0], 0, 0, 0);
        acc[1][1] = __builtin_amdgcn_mfma_f32_16x16x32_bf16(a1, b1, acc[1][1], 0, 0, 0);
        __syncthreads();
    }
    #pragma unroll
    for (int ni = 0; ni < 2; ++ni) {
        int col = col0 + wc + ni * 16 + fr;
        float sc = gg[col] * rsqrtf(vv[col] + 1e-5f);
        float bi = bb[col] - mm[col] * sc;
        #pragma unroll
        for (int mi = 0; mi < 2; ++mi) {
            #pragma unroll
            for (int rgi = 0; rgi < 4; ++rgi) {
                int row = row0 + wr + mi * 16 + (lane >> 4) * 4 + rgi;
                float v = acc[mi][ni][rgi] * sc + bi;
                if (OUT_F32) ((float*)outp)[(size_t)row * N + col] = v;
                else         ((u16*)outp)[(size_t)row * N + col] = f2bf(v);
            }
        }
    }
}

// ---------------- K3a: roi_align -> feats bf16 [NROI][9*256], bin-major ----------------
// One WAVE per roi (4 rois/block); lane handles 4 channels via float4 loads.
// Corner offsets readfirstlane'd -> scalar addressing; weights hoisted per-roi.
__global__ __launch_bounds__(256) void k_roi_feats(
    const float* __restrict__ boxes, const float* __restrict__ fmap,
    u16* __restrict__ feats)
{
    const int t = threadIdx.x, wv = t >> 6, lane = t & 63;
    const int r = blockIdx.x * 4 + wv;
    const int b = rfl_i(r / ROIS_);
    const float* bx = boxes + (size_t)r * 4;
    float x1 = bx[0], y1 = bx[1];
    float rw = fmaxf(bx[2] - x1, 1.0f), rh = fmaxf(bx[3] - y1, 1.0f);
    float sx = rw * (1.0f / 3.0f), sy = rh * (1.0f / 3.0f);
    const float OFFS[6] = {0.25f, 0.75f, 1.25f, 1.75f, 2.25f, 2.75f};
    int xoL[6], xoH[6], yoL[6], yoH[6];
    float lx[6], hx[6], ly[6], hy[6];
    #pragma unroll
    for (int i = 0; i < 6; ++i) {
        float xx = fmaxf(x1 + OFFS[i] * sx, 0.0f);
        int xl = min((int)xx, 13), xh = min(xl + 1, 13);
        float xv = (xl == 13) ? 13.0f : xx;
        lx[i] = xv - (float)xl; hx[i] = 1.0f - lx[i];
        xoL[i] = rfl_i(xl << 8); xoH[i] = rfl_i(xh << 8);       // offsets in floats
        float yy = fmaxf(y1 + OFFS[i] * sy, 0.0f);
        int yl = min((int)yy, 13), yh = min(yl + 1, 13);
        float yv = (yl == 13) ? 13.0f : yy;
        ly[i] = yv - (float)yl; hy[i] = 1.0f - ly[i];
        yoL[i] = rfl_i((yl * 14) << 8); yoH[i] = rfl_i((yh * 14) << 8);
    }
    const float* fb = fmap + ((size_t)b * HW_) * CMID_ + lane * 4;
    f32x4 pooled[9] = {};
    #pragma unroll
    for (int iy = 0; iy < 6; ++iy) {
        #pragma unroll
        for (int ix = 0; ix < 6; ++ix) {
            f32x4 f00 = *reinterpret_cast<const f32x4*>(fb + yoL[iy] + xoL[ix]);
            f32x4 f01 = *reinterpret_cast<const f32x4*>(fb + yoL[iy] + xoH[ix]);
            f32x4 f10 = *reinterpret_cast<const f32x4*>(fb + yoH[iy] + xoL[ix]);
            f32x4 f11 = *reinterpret_cast<const f32x4*>(fb + yoH[iy] + xoH[ix]);
            float w00 = hy[iy] * hx[ix], w01 = hy[iy] * lx[ix];
            float w10 = ly[iy] * hx[ix], w11 = ly[iy] * lx[ix];
            const int bin = (iy >> 1) * 3 + (ix >> 1);
            pooled[bin] += f00 * w00 + f01 * w01 + f10 * w10 + f11 * w11;
        }
    }
    u16* fo = feats + (size_t)r * FEAT_ + lane * 4;
    #pragma unroll
    for (int bin = 0; bin < 9; ++bin) {
        f32x4 p = pooled[bin] * 0.25f;
        ushort4 s;
        s.x = f2bf(p[0]); s.y = f2bf(p[1]); s.z = f2bf(p[2]); s.w = f2bf(p[3]);
        *reinterpret_cast<ushort4*>(fo + (size_t)bin * 256) = s;
    }
}

// ---------------- K3b: FC GEMM  out[NROI,27] = feats[NROI,2304] * wfcb[32,2304]^T + bfc ----
__global__ __launch_bounds__(256) void k_fc(
    const u16* __restrict__ feats, const u16* __restrict__ wfcb,
    const float* __restrict__ bfc, float* __restrict__ out)
{
    __shared__ u16 As[64][72];
    __shared__ u16 Bs[32][72];
    const int row0 = blockIdx.x * 64;
    const int t = threadIdx.x, wave = t >> 6, lane = t & 63;
    const int fr = lane & 15, fk = (lane >> 4) * 8;
    const int ar = t >> 2, ak = (t & 3) * 8;
    const int br = t >> 3, bk = (t & 7) * 8;
    f32x4 acc[2] = {};
    const u16* Ap = feats + (size_t)(row0 + ar) * FEAT_ + ak;
    const u16* Bp = wfcb + (size_t)br * FEAT_ + bk;
    uint4 a0n = *reinterpret_cast<const uint4*>(Ap);
    uint4 a1n = *reinterpret_cast<const uint4*>(Ap + 32);
    uint4 b0n = *reinterpret_cast<const uint4*>(Bp);
    for (int k0 = 0; k0 < FEAT_; k0 += 64) {
        *reinterpret_cast<uint4*>(&As[ar][ak]) = a0n;
        *reinterpret_cast<uint4*>(&As[ar][ak + 32]) = a1n;
        *reinterpret_cast<uint4*>(&Bs[br][bk]) = b0n;
        __syncthreads();
        if (k0 + 64 < FEAT_) {
            a0n = *reinterpret_cast<const uint4*>(Ap + k0 + 64);
            a1n = *reinterpret_cast<const uint4*>(Ap + k0 + 96);
            b0n = *reinterpret_cast<const uint4*>(Bp + k0 + 64);
        }
        #pragma unroll
        for (int kk = 0; kk < 64; kk += 32) {
            bf16x8 a  = *reinterpret_cast<bf16x8*>(&As[wave * 16 + fr][fk + kk]);
            bf16x8 b0 = *reinterpret_cast<bf16x8*>(&Bs[fr][fk + kk]);
            bf16x8 b1 = *reinterpret_cast<bf16x8*>(&Bs[16 + fr][fk + kk]);
            acc[0] = __builtin_amdgcn_mfma_f32_16x16x32_bf16(a, b0, acc[0], 0, 0, 0);
            acc[1] = __builtin_amdgcn_mfma_f32_16x16x32_bf16(a, b1, acc[1], 0, 0, 0);
        }
        __syncthreads();
    }
    #pragma unroll
    for (int ni = 0; ni < 2; ++ni) {
        int col = ni * 16 + fr;
        if (col < NCLS_) {
            float bi = bfc[col];
            #pragma unroll
            for (int rgi = 0; rgi < 4; ++rgi) {
                int row = row0 + wave * 16 + (lane >> 4) * 4 + rgi;
                out[(size_t)row * NCLS_ + col] = acc[ni][rgi] + bi;
            }
        }
    }
}

extern "C" void kernel_launch(void* const* d_in, const int* in_sizes, int n_in,
                              void* d_out, int out_size, void* d_ws, size_t ws_size,
                              hipStream_t stream) {
    const float* boxes   = (const float*)d_in[0];
    const float* fmap_in = (const float*)d_in[1];
    const float* w1 = (const float*)d_in[2];
    const float* g1 = (const float*)d_in[3];
    const float* b1 = (const float*)d_in[4];
    const float* m1 = (const float*)d_in[5];
    const float* v1 = (const float*)d_in[6];
    const float* w2 = (const float*)d_in[7];
    const float* g2 = (const float*)d_in[8];
    const float* b2 = (const float*)d_in[9];
    const float* m2 = (const float*)d_in[10];
    const float* v2 = (const float*)d_in[11];
    const float* wfc = (const float*)d_in[12];
    const float* bfc = (const float*)d_in[13];

    char* ws = (char*)d_ws;
    u16*   Anhwc     = (u16*)(ws + 0);               //  6,422,528 B
    float* fmapw_f32 = (float*)(ws + 0);             //  3,211,264 B (aliases Anhwc; Anhwc dead after conv1)
    u16*   h         = (u16*)(ws + 6422528);         //  6,422,528 B
    u16*   w1b       = (u16*)(ws + 14450688);        //  2,097,152 B
    u16*   w2b       = (u16*)(ws + 16547840);        //    524,288 B
    u16*   wfcb      = (u16*)(ws + 17072128);        //    147,456 B
    u16*   feats     = (u16*)(ws + 17219584);        // 72,253,440 B  (total ~89.5 MB)

    hipLaunchKernelGGL(k_f32_to_bf16, dim3((CIN_ * CIN_) / 256), dim3(256), 0, stream,
                       w1, w1b);
    hipLaunchKernelGGL(k_f32_to_bf16, dim3((CMID_ * CIN_) / 256), dim3(256), 0, stream,
                       w2, w2b);
    hipLaunchKernelGGL(k_prep_wfc, dim3((32 * FEAT_) / 256), dim3(256), 0, stream,
                       wfc, wfcb);
    hipLaunchKernelGGL(k_nchw_to_nhwc, dim3((M_ * CIN_) / 256), dim3(256), 0, stream,
                       fmap_in, Anhwc);
    hipLaunchKernelGGL((k_gemm_bn<false>), dim3(CIN_ / 64, M_ / 64), dim3(256), 0, stream,
                       Anhwc, w1b, g1, b1, m1, v1, (void*)h, CIN_, CIN_);
    hipLaunchKernelGGL((k_gemm_bn<true>), dim3(CMID_ / 64, M_ / 64), dim3(256), 0, stream,
                       h, w2b, g2, b2, m2, v2, (void*)fmapw_f32, CMID_, CIN_);
    hipLaunchKernelGGL(k_roi_feats, dim3(NROI_ / 4), dim3(256), 0, stream,
                       boxes, fmapw_f32, feats);
    hipLaunchKernelGGL(k_fc, dim3(NROI_ / 64), dim3(256), 0, stream,
                       feats, wfcb, bfc, (float*)d_out);
}